// Round 3
// baseline (273.180 us; speedup 1.0000x reference)
//
#include <hip/hip_runtime.h>
#include <hip/hip_bf16.h>
#include <stdint.h>

#define BATCH 64
#define CIN   64
#define LEN   4096
#define COUT  128
#define KW    7
#define LPOOL 2048
#define RROWS 72   // staged halo rows per sub-tile: p = l0-4+r, r in [0,72)
#define NT    4    // l sub-tiles of 64 per block

typedef __bf16 v8bf __attribute__((ext_vector_type(8)));
typedef unsigned short v8us __attribute__((ext_vector_type(8)));
typedef float  v4f  __attribute__((ext_vector_type(4)));

// Convert conv_w [COUT][CIN][KW] fp32 -> Wt [KW][COUT][CIN] bf16 (RNE).
__global__ __launch_bounds__(256)
void wconv_kernel(const float* __restrict__ W, ushort* __restrict__ Wt) {
    int i = blockIdx.x * 256 + threadIdx.x;
    if (i >= COUT * CIN * KW) return;
    int co  = i / (CIN * KW);
    int rem = i - co * (CIN * KW);
    int ci  = rem / KW;
    int k   = rem - ci * KW;
    uint u = __float_as_uint(W[i]);
    uint r = (u + 0x7FFFu + ((u >> 16) & 1u)) >> 16;   // RNE to bf16
    Wt[(k * COUT + co) * CIN + ci] = (ushort)r;
}

// Fused: BN -> sign -> conv (bf16 MFMA) -> alpha -> PReLU -> maxpool2.
// Block: 256 threads, 4 l-sub-tiles of 64, double-buffered sign staging.
// Pipeline per iter: issue glb loads(t+1) | MFMA(t) | barrier |
//                    binarize+ldswrite(t+1) + epilogue-store(t) | barrier.
__global__ __launch_bounds__(256, 4)
void conv_kernel(const float* __restrict__ I,
                 const float* __restrict__ bn_g, const float* __restrict__ bn_b,
                 const float* __restrict__ bn_m, const float* __restrict__ bn_v,
                 const ushort* __restrict__ Wt,
                 const float* __restrict__ alpha, const float* __restrict__ prelu,
                 float* __restrict__ out) {
    __shared__ __align__(16) ushort stg[2][RROWS * 72];  // pitch 72 ushorts = 144B
    __shared__ float4 bnc[CIN];                          // (scale, mean, beta, -)

    int tid = threadIdx.x;
    int b = blockIdx.y, bx = blockIdx.x;
    int l0base = bx * (64 * NT);

    if (tid < CIN) {
        // bit-exact vs np fp32: gamma / sqrt(var + eps)
        float s = __fdiv_rn(bn_g[tid], __fsqrt_rn(__fadd_rn(bn_v[tid], 1e-5f)));
        bnc[tid] = make_float4(s, bn_m[tid], bn_b[tid], 0.f);
    }
    __syncthreads();

    // ---- staging lanes: thread owns ci-group g (8 ci), rows r=(tid&31)+32*it ----
    int g = tid >> 5;
    int rbase = tid & 31;
    const float* Ib = I + (size_t)b * CIN * LEN + (size_t)g * 8 * LEN;

    float v[3][8];
    bool inb[3];

    auto stage_regs = [&](int t) {
        int l0 = l0base + t * 64;
        #pragma unroll
        for (int it = 0; it < 3; ++it) {
            int r = rbase + 32 * it;
            int p = l0 - 4 + r;
            inb[it] = (r < RROWS) && (p >= 0) && (p < LEN);
            #pragma unroll
            for (int j = 0; j < 8; ++j)
                v[it][j] = inb[it] ? Ib[j * LEN + p] : 0.f;
        }
    };
    auto binwrite = [&](int buf) {
        #pragma unroll
        for (int it = 0; it < 3; ++it) {
            int r = rbase + 32 * it;
            if (r < RROWS) {
                v8us u;
                #pragma unroll
                for (int j = 0; j < 8; ++j) {
                    float4 c = bnc[8 * g + j];
                    // (v - mean) * scale + beta, exact np rounding (sign boundary)
                    float x = __fadd_rn(__fmul_rn(__fsub_rn(v[it][j], c.y), c.x), c.z);
                    ushort s = x > 0.f ? (ushort)0x3F80 : (x < 0.f ? (ushort)0xBF80 : (ushort)0);
                    if (!inb[it]) s = 0;
                    u[j] = s;
                }
                *(v8us*)(&stg[buf][r * 72 + g * 8]) = u;
            }
        }
    };

    // ---- MFMA lane mapping ----
    int lane = tid & 63, wave = tid >> 6;
    int quad = lane >> 4, lr = lane & 15;
    int cout0 = wave * 32;
    // per (k,h,nt): Wt + k*COUT*CIN + (cout0 + nt*16 + lr)*CIN + h*32 + quad*8
    const ushort* wbase = Wt + ((size_t)cout0 + lr) * CIN + quad * 8;

    float pw  = prelu[0];
    float al0 = alpha[cout0 + lr];
    float al1 = alpha[cout0 + 16 + lr];
    float* obase = out + ((size_t)b * COUT) * LPOOL + bx * (32 * NT);

    v4f acc[4][2];

    // ---- prologue ----
    stage_regs(0);
    binwrite(0);
    __syncthreads();

    for (int t = 0; t < NT; ++t) {
        if (t + 1 < NT) stage_regs(t + 1);   // issue glb loads; land under MFMA(t)

        // ---- MFMA(t): k-level weight double-buffer from L2 ----
        #pragma unroll
        for (int mt = 0; mt < 4; ++mt) { acc[mt][0] = (v4f)0.f; acc[mt][1] = (v4f)0.f; }

        v8bf wcur[2][2], wnxt[2][2];
        #pragma unroll
        for (int h = 0; h < 2; ++h)
            #pragma unroll
            for (int n2 = 0; n2 < 2; ++n2)
                wcur[h][n2] = *(const v8bf*)(wbase + h * 32 + n2 * 16 * CIN);

        int buf = t & 1;
        #pragma unroll
        for (int k = 0; k < KW; ++k) {
            if (k + 1 < KW) {
                const ushort* wk = wbase + (size_t)(k + 1) * COUT * CIN;
                #pragma unroll
                for (int h = 0; h < 2; ++h)
                    #pragma unroll
                    for (int n2 = 0; n2 < 2; ++n2)
                        wnxt[h][n2] = *(const v8bf*)(wk + h * 32 + n2 * 16 * CIN);
            }
            #pragma unroll
            for (int h = 0; h < 2; ++h) {
                int cibase = h * 32 + quad * 8;
                #pragma unroll
                for (int mt = 0; mt < 4; ++mt) {
                    // A row for output l=mt*16+lr at tap k: r = l + k + 1
                    v8bf a = *(const v8bf*)(&stg[buf][(mt * 16 + lr + k + 1) * 72 + cibase]);
                    acc[mt][0] = __builtin_amdgcn_mfma_f32_16x16x32_bf16(a, wcur[h][0], acc[mt][0], 0, 0, 0);
                    acc[mt][1] = __builtin_amdgcn_mfma_f32_16x16x32_bf16(a, wcur[h][1], acc[mt][1], 0, 0, 0);
                }
            }
            #pragma unroll
            for (int h = 0; h < 2; ++h)
                #pragma unroll
                for (int n2 = 0; n2 < 2; ++n2)
                    wcur[h][n2] = wnxt[h][n2];
        }
        __syncthreads();   // all waves done reading stg[buf]

        if (t + 1 < NT) binwrite((t + 1) & 1);

        // ---- epilogue(t): alpha * PReLU, in-lane pool, float2 global stores ----
        // quad holds l = mt*16 + quad*4 + {0..3} -> pooled lp = mt*8 + quad*2 + {0,1}
        float* ob = obase + t * 32;
        #pragma unroll
        for (int n2 = 0; n2 < 2; ++n2) {
            float al = n2 ? al1 : al0;
            int co = cout0 + n2 * 16 + lr;
            float* oc = ob + (size_t)co * LPOOL + quad * 2;
            #pragma unroll
            for (int mt = 0; mt < 4; ++mt) {
                float v0 = acc[mt][n2][0] * al; v0 = v0 > 0.f ? v0 : pw * v0;
                float v1 = acc[mt][n2][1] * al; v1 = v1 > 0.f ? v1 : pw * v1;
                float v2 = acc[mt][n2][2] * al; v2 = v2 > 0.f ? v2 : pw * v2;
                float v3 = acc[mt][n2][3] * al; v3 = v3 > 0.f ? v3 : pw * v3;
                *(float2*)(oc + mt * 8) = make_float2(fmaxf(v0, v1), fmaxf(v2, v3));
            }
        }
        __syncthreads();   // binwrite(t+1) visible before MFMA(t+1)
    }
}

extern "C" void kernel_launch(void* const* d_in, const int* in_sizes, int n_in,
                              void* d_out, int out_size, void* d_ws, size_t ws_size,
                              hipStream_t stream) {
    const float* I      = (const float*)d_in[0];
    const float* bn_g   = (const float*)d_in[1];
    const float* bn_b   = (const float*)d_in[2];
    const float* bn_m   = (const float*)d_in[3];
    const float* bn_v   = (const float*)d_in[4];
    const float* conv_w = (const float*)d_in[5];
    const float* alpha  = (const float*)d_in[6];
    const float* prelu  = (const float*)d_in[7];
    float* out = (float*)d_out;

    ushort* Wt = (ushort*)d_ws;   // 7*128*64*2 = 114688 bytes

    wconv_kernel<<<(COUT * CIN * KW + 255) / 256, 256, 0, stream>>>(conv_w, Wt);
    dim3 grid(LEN / (64 * NT), BATCH);
    conv_kernel<<<grid, 256, 0, stream>>>(I, bn_g, bn_b, bn_m, bn_v, Wt, alpha, prelu, out);
}